// Round 1
// 146.869 us; speedup vs baseline: 1.0473x; 1.0473x over previous
//
#include <hip/hip_runtime.h>

// VectorQuantizer: fp32 buffers, low-precision-valued data. in [32,64,64,64]
// NCHW, emb [512,64], out fp32. np-ref computes distances in fp32 -> argmin
// must match numpy bit-for-bit. Proven numerics (R5/R6/R8/R9, absmax 0.0):
// hi/lo bf16 split (exact products), filter c2 = b2 - 2*(xh.eh+xh.el+xl.eh);
// ambiguity resolved by bit-exact numpy fp32 replica (top-2 re-rank, rare
// full wave rescan).
// R11: VALU-bound (VALUBusy 60% vs MfmaUtil 11.6%) on the top-3 select
// network. Drop the +4 bias so |c2|~0.02-0.1, pack column index into the
// low 9 mantissa bits (v_and_or_b32, perturbation <= ~2e-5 near the min),
// then top-3 tracking is 3 ops (v_med3_f32 x2 + v_min_f32) instead of a
// 9-op compare/select net, and the butterfly merge is 6 ops/stage instead
// of ~21. Indices fall out of bits(m1)&0x1FF. MARGIN widened 1e-4 -> 2.5e-4
// to absorb packing error (> 2*(filter 5e-5 + pack 2e-5), 1.8x headroom);
// ambiguous rows still resolved by the exact replica paths.

#define NEMB 512
#define DIM 64
#define ROWS 64
#define MARGIN 2.5e-4f

typedef unsigned int u32;
typedef unsigned short u16;
typedef __attribute__((ext_vector_type(8))) short bf16x8;
typedef __attribute__((ext_vector_type(4))) float f32x4;

__device__ __forceinline__ u32 f2bfbits(float f) {  // fp32 -> bf16 bits (RNE)
  u32 u = __float_as_uint(f);
  return (u + 0x7FFFu + ((u >> 16) & 1u)) >> 16;
}
__device__ __forceinline__ float bfbits2f(u32 b) {
  return __uint_as_float(b << 16);
}
__device__ __forceinline__ float fmed3(float a, float b, float c) {
  return __builtin_amdgcn_fmed3f(a, b, c);
}

// ---- prep: swizzled hi/lo bf16 codebook + exact numpy-replica b2 ----
// off(g,p,f,r,e) = g*2048 + p*1024 + f*512 + r*32 + e   (u16 units)
//   g=row>>4, r=row&15, p=plane(0 hi,1 lo), f=k>>5, e=k&31.
// A wave's 16-row fragment load at fixed (p,f) is 1KB contiguous.
__global__ void vq_prep(const float* __restrict__ emb, u16* __restrict__ swz,
                        float* __restrict__ b2) {
#pragma clang fp contract(off)
  const int n = blockIdx.x * 256 + threadIdx.x;
  if (n >= NEMB) return;
  const float* e = emb + n * DIM;
  float rr[8];
#pragma unroll
  for (int j = 0; j < 8; ++j) {
    float acc = e[j] * e[j];
#pragma unroll
    for (int i = 8; i < DIM; i += 8) acc = acc + e[i + j] * e[i + j];
    rr[j] = acc;
  }
  b2[n] = ((rr[0] + rr[1]) + (rr[2] + rr[3])) + ((rr[4] + rr[5]) + (rr[6] + rr[7]));
  const int g = n >> 4, r = n & 15;
  u16* gb = swz + (g << 11) + (r << 5);
#pragma unroll
  for (int k = 0; k < DIM; ++k) {
    const u32 h = f2bfbits(e[k]);
    const float res = e[k] - bfbits2f(h);  // exact (Sterbenz)
    const int off = ((k >> 5) << 9) + (k & 31);
    gb[off] = (u16)h;                     // hi plane
    gb[1024 + off] = (u16)f2bfbits(res);  // lo plane
  }
}

// ---- main kernel: 64 rows/block.
// wave wv: row-half rh=wv&1 (tiles 2rh,2rh+1), col-half ch=wv>>1 (256 cols).
__global__ __launch_bounds__(256, 1) void vq_mfma(
    const float* __restrict__ in, const float* __restrict__ emb,
    const u16* __restrict__ swz, const float* __restrict__ b2g,
    float* __restrict__ out) {
#pragma clang fp contract(off)
  __shared__ float xs[ROWS][DIM + 2];
  __shared__ float a2s[ROWS];
  __shared__ float b2s[NEMB];
  __shared__ float wsv1[ROWS][2], wsv2[ROWS][2], wsv3[ROWS][2];
  __shared__ int win[ROWS];
  __shared__ int queue[ROWS];
  __shared__ int qcnt;

  const int tid = threadIdx.x;
  const int blk = blockIdx.x;
  const int b = blk >> 6;
  const int hw0 = (blk & 63) << 6;
  const float* xbase = in + ((size_t)b << 18) + hw0;

  for (int i = tid; i < NEMB; i += 256) b2s[i] = b2g[i];
  if (tid == 0) qcnt = 0;

  {  // stage x tile (64 consecutive floats per wave = coalesced)
    const int h = tid & 63, cg = tid >> 6;
#pragma unroll
    for (int i = 0; i < 16; ++i) {
      const int c = cg + (i << 2);
      xs[h][c] = xbase[((size_t)c << 12) + h];
    }
  }
  __syncthreads();

  if (tid < ROWS) {  // a2 numpy pairwise-8 replica (re-rank input)
    const float* x = xs[tid];
    float rr[8];
#pragma unroll
    for (int j = 0; j < 8; ++j) {
      float acc = x[j] * x[j];
#pragma unroll
      for (int i = 8; i < DIM; i += 8) acc = acc + x[i + j] * x[i + j];
      rr[j] = acc;
    }
    a2s[tid] = ((rr[0] + rr[1]) + (rr[2] + rr[3])) + ((rr[4] + rr[5]) + (rr[6] + rr[7]));
  }

  const int lane = tid & 63;
  const int wv = tid >> 6;
  const int rh = wv & 1;   // row-half
  const int ch = wv >> 1;  // col-half
  const int rowl = lane & 15;
  const int quad = lane >> 4;

  // A fragments for this wave's 2 row-tiles: A[m=lane&15][k=quad*8+j]
  bf16x8 ah[2][2], al[2][2];
#pragma unroll
  for (int ta = 0; ta < 2; ++ta) {
    const int a = (rh << 1) + ta;
    const float* xr = xs[(a << 4) + rowl];
#pragma unroll
    for (int f = 0; f < 2; ++f) {
      const int k0 = (f << 5) + (quad << 3);
      bf16x8 vh, vl;
#pragma unroll
      for (int j = 0; j < 8; ++j) {
        const float xv = xr[k0 + j];
        const u32 h = f2bfbits(xv);
        const float res = xv - bfbits2f(h);  // exact
        vh[j] = (short)h;
        vl[j] = (short)f2bfbits(res);
      }
      ah[ta][f] = vh;
      al[ta][f] = vl;
    }
  }

  // ---- single pass over 256 cols: streaming top-3, index packed in the
  // low 9 mantissa bits of the (small-magnitude) filter value ----
  float v1[8], v2[8], v3[8];
#pragma unroll
  for (int i = 0; i < 8; ++i) { v1[i] = 3.0e38f; v2[i] = 3.0e38f; v3[i] = 3.0e38f; }

  const u16* cbase = swz + ((size_t)(ch << 4) << 11);
  const int off = (rowl << 5) + (quad << 3);

  // preload group 0; rolled loop (unroll 1!) with 1-deep clamped prefetch
  bf16x8 nh0 = *(const bf16x8*)(cbase + off);
  bf16x8 nh1 = *(const bf16x8*)(cbase + 512 + off);
  bf16x8 nl0 = *(const bf16x8*)(cbase + 1024 + off);
  bf16x8 nl1 = *(const bf16x8*)(cbase + 1536 + off);

#pragma unroll 1
  for (int t = 0; t < 16; ++t) {
    const bf16x8 bh0 = nh0, bh1 = nh1, bl0 = nl0, bl1 = nl1;
    {  // prefetch next group (clamped: last iter re-loads, harmless)
      const int tn = t < 15 ? t + 1 : 15;
      const u16* gb = cbase + (tn << 11);
      nh0 = *(const bf16x8*)(gb + off);
      nh1 = *(const bf16x8*)(gb + 512 + off);
      nl0 = *(const bf16x8*)(gb + 1024 + off);
      nl1 = *(const bf16x8*)(gb + 1536 + off);
    }
    const int n = (ch << 8) + (t << 4) + rowl;
    const float b2v = b2s[n];
    const u32 nb = (u32)n;
#pragma unroll
    for (int ta = 0; ta < 2; ++ta) {
      f32x4 acc = {0.f, 0.f, 0.f, 0.f};
      acc = __builtin_amdgcn_mfma_f32_16x16x32_bf16(ah[ta][0], bh0, acc, 0, 0, 0);
      acc = __builtin_amdgcn_mfma_f32_16x16x32_bf16(ah[ta][1], bh1, acc, 0, 0, 0);
      acc = __builtin_amdgcn_mfma_f32_16x16x32_bf16(ah[ta][0], bl0, acc, 0, 0, 0);
      acc = __builtin_amdgcn_mfma_f32_16x16x32_bf16(ah[ta][1], bl1, acc, 0, 0, 0);
      acc = __builtin_amdgcn_mfma_f32_16x16x32_bf16(al[ta][0], bh0, acc, 0, 0, 0);
      acc = __builtin_amdgcn_mfma_f32_16x16x32_bf16(al[ta][1], bh1, acc, 0, 0, 0);
#pragma unroll
      for (int r = 0; r < 4; ++r) {
        const int i = (ta << 2) + r;
        const float c2 = fmaf(-2.0f, acc[r], b2v);
        const float cp =
            __uint_as_float((__float_as_uint(c2) & 0xFFFFFE00u) | nb);
        // streaming top-3 (v1<=v2<=v3 invariant): med3/min network
        v3[i] = fmed3(v2[i], cp, v3[i]);
        v2[i] = fmed3(v1[i], cp, v2[i]);
        v1[i] = fminf(v1[i], cp);
      }
    }
  }

  // butterfly top-3 merge across the 16 column lanes; packed values carry
  // their indices, so the merge is pure med3/min (exact streaming top-3)
#pragma unroll
  for (int m = 1; m < 16; m <<= 1) {
#pragma unroll
    for (int i = 0; i < 8; ++i) {
      const float o1 = __shfl_xor(v1[i], m);
      const float o2 = __shfl_xor(v2[i], m);
      const float o3 = __shfl_xor(v3[i], m);
      // insert o1 (full), o2 (can't become m1), o3 (can only touch m3)
      v3[i] = fmed3(v2[i], o1, v3[i]);
      v2[i] = fmed3(v1[i], o1, v2[i]);
      v1[i] = fminf(v1[i], o1);
      v3[i] = fmed3(v2[i], o2, v3[i]);
      v2[i] = fmed3(v1[i], o2, v2[i]);
      v3[i] = fminf(v3[i], o3);
    }
  }
  if (rowl == 0) {  // publish per col-half slot
#pragma unroll
    for (int ta = 0; ta < 2; ++ta)
#pragma unroll
      for (int r = 0; r < 4; ++r) {
        const int row = (((rh << 1) + ta) << 4) + (quad << 2) + r;
        const int i = (ta << 2) + r;
        wsv1[row][ch] = v1[i]; wsv2[row][ch] = v2[i]; wsv3[row][ch] = v3[i];
      }
  }
  __syncthreads();

  // ---- cross-half merge + decision ----
  if (tid < ROWS) {
    float m1 = wsv1[tid][0], m2v = wsv2[tid][0], m3 = wsv3[tid][0];
    const float u1 = wsv1[tid][1], u2 = wsv2[tid][1], u3 = wsv3[tid][1];
    m3 = fmed3(m2v, u1, m3);
    m2v = fmed3(m1, u1, m2v);
    m1 = fminf(m1, u1);
    m3 = fmed3(m2v, u2, m3);
    m2v = fmed3(m1, u2, m2v);
    m3 = fminf(m3, u3);
    const int j1 = (int)(__float_as_uint(m1) & 0x1FFu);
    const int j2 = (int)(__float_as_uint(m2v) & 0x1FFu);

    if (m2v > m1 + MARGIN) {
      win[tid] = j1;  // unambiguous
    } else if (m3 > m1 + MARGIN) {
      // true argmin in {j1,j2}: exact numpy fp32 re-rank, first-min tie rule
      const float a2 = a2s[tid];
      const float* x = xs[tid];
      const float* e1p = emb + (j1 << 6);
      const float* e2p = emb + (j2 << 6);
      float acc1 = 0.f, acc2 = 0.f;
#pragma unroll
      for (int j = 0; j < DIM; ++j) {
        acc1 = fmaf(x[j], e1p[j], acc1);
        acc2 = fmaf(x[j], e2p[j], acc2);
      }
      const float t1 = a2 + b2g[j1];
      const float t2 = a2 + b2g[j2];
      const float d1 = t1 - 2.0f * acc1;
      const float d2 = t2 - 2.0f * acc2;
      win[tid] = (d2 < d1 || (d2 == d1 && j2 < j1)) ? j2 : j1;
    } else {  // >=3 within margin: full exact rescan (rare)
      const int p = atomicAdd(&qcnt, 1);
      queue[p] = tid;
    }
  }
  __syncthreads();

  // ---- rare fallback: wave-cooperative bit-exact numpy fp32 rescan ----
  const int nq = qcnt;
  for (int qi = wv; qi < nq; qi += 4) {
    const int row = queue[qi];
    const float a2 = a2s[row];
    const float* x = xs[row];  // broadcast LDS reads
    float bd = 3.0e38f;
    int bi = 1 << 30;
#pragma unroll 1
    for (int c = 0; c < 8; ++c) {
      const int k = (c << 6) + lane;
      const float* e = emb + (k << 6);
      float acc = 0.f;
#pragma unroll
      for (int j = 0; j < DIM; ++j) acc = fmaf(x[j], e[j], acc);
      const float tt = a2 + b2g[k];  // fl(a2+b2)
      const float u = 2.0f * acc;    // fl(2ab)
      const float d = tt - u;        // fl(t-u)
      if (d < bd || (d == bd && k < bi)) { bd = d; bi = k; }
    }
#pragma unroll
    for (int m = 1; m < 64; m <<= 1) {  // numpy first-min tie rule
      const float od = __shfl_xor(bd, m);
      const int oi = __shfl_xor(bi, m);
      if (od < bd || (od == bd && oi < bi)) { bd = od; bi = oi; }
    }
    if (lane == 0) win[row] = bi;
  }
  __syncthreads();

  {  // fold q into xs in place: coalesced emb row reads, fl(x + fl(q-x))
    const int r0 = wv << 4;
#pragma unroll 1
    for (int r = 0; r < 16; ++r) {
      const int row = r0 + r;
      const float* eW = emb + (win[row] << 6);
      const float xv = xs[row][lane];
      const float qv = eW[lane];
      xs[row][lane] = xv + (qv - xv);
    }
  }
  __syncthreads();

  {  // store: coalesced (lane = h)
    const int h = tid & 63, cg = tid >> 6;
    float* obase = out + ((size_t)b << 18) + hw0;
#pragma unroll
    for (int i = 0; i < 16; ++i) {
      const int c = cg + (i << 2);
      obase[((size_t)c << 12) + h] = xs[h][c];
    }
  }
}

// ---- fallback (R3, passed absmax 0.0): used only if ws too small ----
__global__ __launch_bounds__(256, 2) void vq_exact(
    const float* __restrict__ in, const float* __restrict__ emb,
    float* __restrict__ out, int nvec) {
#pragma clang fp contract(off)
  __shared__ float b2s[NEMB];
  for (int r = threadIdx.x; r < NEMB; r += 256) {
    const float* e = emb + r * DIM;
    float rr[8];
#pragma unroll
    for (int j = 0; j < 8; ++j) {
      float acc = e[j] * e[j];
#pragma unroll
      for (int i = 8; i < DIM; i += 8) acc = acc + e[i + j] * e[i + j];
      rr[j] = acc;
    }
    b2s[r] = ((rr[0] + rr[1]) + (rr[2] + rr[3])) + ((rr[4] + rr[5]) + (rr[6] + rr[7]));
  }
  __syncthreads();
  const int vec = blockIdx.x * 256 + threadIdx.x;
  if (vec >= nvec) return;
  const int b = vec >> 12, hw = vec & 4095;
  const float* xp = in + ((size_t)b << 18) + hw;
  float x[DIM];
#pragma unroll
  for (int j = 0; j < DIM; ++j) x[j] = xp[(size_t)j << 12];
  float a2;
  {
    float rr[8];
#pragma unroll
    for (int j = 0; j < 8; ++j) {
      float acc = x[j] * x[j];
#pragma unroll
      for (int i = 8; i < DIM; i += 8) acc = acc + x[i + j] * x[i + j];
      rr[j] = acc;
    }
    a2 = ((rr[0] + rr[1]) + (rr[2] + rr[3])) + ((rr[4] + rr[5]) + (rr[6] + rr[7]));
  }
  float best = 3.0e38f;
  int bi = 0;
  for (int k0 = 0; k0 < NEMB; k0 += 4) {
    const float *e0 = emb + ((k0 + 0) << 6), *e1 = emb + ((k0 + 1) << 6);
    const float *e2 = emb + ((k0 + 2) << 6), *e3 = emb + ((k0 + 3) << 6);
    float c0 = 0.f, c1 = 0.f, c2 = 0.f, c3 = 0.f;
#pragma unroll
    for (int j = 0; j < DIM; ++j) {
      const float xj = x[j];
      c0 = fmaf(xj, e0[j], c0); c1 = fmaf(xj, e1[j], c1);
      c2 = fmaf(xj, e2[j], c2); c3 = fmaf(xj, e3[j], c3);
    }
    float cc[4] = {c0, c1, c2, c3};
#pragma unroll
    for (int q = 0; q < 4; ++q) {
      const float t = a2 + b2s[k0 + q];
      const float u = 2.0f * cc[q];
      const float d = t - u;
      if (d < best) { best = d; bi = k0 + q; }
    }
  }
  const float* ew = emb + (bi << 6);
  float* op = out + ((size_t)b << 18) + hw;
#pragma unroll
  for (int c = 0; c < DIM; ++c) {
    const float xv = x[c];
    op[(size_t)c << 12] = xv + (ew[c] - xv);
  }
}

extern "C" void kernel_launch(void* const* d_in, const int* in_sizes, int n_in,
                              void* d_out, int out_size, void* d_ws, size_t ws_size,
                              hipStream_t stream) {
  const float* in;
  const float* emb;
  int in_elems;
  if (n_in >= 2 && in_sizes[0] == NEMB * DIM && in_sizes[1] != NEMB * DIM) {
    emb = (const float*)d_in[0]; in = (const float*)d_in[1]; in_elems = in_sizes[1];
  } else {
    in = (const float*)d_in[0]; emb = (const float*)d_in[1]; in_elems = in_sizes[0];
  }
  float* out = (float*)d_out;
  const int nvec = in_elems / DIM;
  const size_t swzB = (size_t)NEMB * DIM * 2 * sizeof(u16);  // hi+lo swizzled
  const size_t need = swzB + NEMB * sizeof(float);

  if (ws_size >= need && d_ws != nullptr && (nvec % ROWS) == 0 &&
      (in_elems % (DIM * 4096)) == 0) {
    u16* swz = (u16*)d_ws;
    float* b2 = (float*)((char*)d_ws + swzB);
    vq_prep<<<dim3(2), dim3(256), 0, stream>>>(emb, swz, b2);
    vq_mfma<<<dim3(nvec / ROWS), dim3(256), 0, stream>>>(in, emb, swz, b2, out);
  } else {
    vq_exact<<<dim3((nvec + 255) / 256), dim3(256), 0, stream>>>(in, emb, out, nvec);
  }
}

// Round 2
// 145.296 us; speedup vs baseline: 1.0587x; 1.0108x over previous
//
#include <hip/hip_runtime.h>

// VectorQuantizer: fp32 buffers, low-precision-valued data. in [32,64,64,64]
// NCHW, emb [512,64], out fp32. np-ref computes distances in fp32 -> argmin
// must match numpy bit-for-bit. Proven numerics (R5/R6/R8/R9, absmax 0.0):
// hi/lo bf16 split (exact products); ambiguity resolved by bit-exact numpy
// fp32 replica (top-2 re-rank, rare full wave rescan).
// R11 (proven): index packed in low 9 mantissa bits, med3/min top-3 network.
// R12: latency-bound (MFMA 12%, VALU 33%, HBM 8%, occ 24% -- all low).
//  (a) epilogue fold was a serial LDS->global dependent chain (unroll 1):
//      now batched (16 win reads, 16 concurrent emb-row loads, one drain);
//  (b) hot loop: 2-deep codebook prefetch (two register sets, 2-phase body)
//      to cover ~200-300cy L2 latency (1-deep covered only ~150cy);
//  (c) max-domain filter: acc' = dot - b2/2 via MFMA acc INIT = -b2/2
//      (same b2 for all 4 acc regs of a lane), killing the 8 fmaf/iter;
//      selection tracks top-3 MAXIMA (med3/max), HMARGIN = MARGIN/2 domain.
// Packing bound (max domain): |M|<=~0.2 -> 512ulp <= 1.5e-5; filter err
// 2.5e-5; per-cand 4e-5... wait 8.05e-5 total c2-halved; HMARGIN 1.45e-4
// = 1.8x bound (same safety ratio as proven R11 2.5e-4 vs 1.4e-4).

#define NEMB 512
#define DIM 64
#define ROWS 64
#define HMARGIN 1.45e-4f  // margin in acc' = -c2/2 (max) domain

typedef unsigned int u32;
typedef unsigned short u16;
typedef __attribute__((ext_vector_type(8))) short bf16x8;
typedef __attribute__((ext_vector_type(4))) float f32x4;

__device__ __forceinline__ u32 f2bfbits(float f) {  // fp32 -> bf16 bits (RNE)
  u32 u = __float_as_uint(f);
  return (u + 0x7FFFu + ((u >> 16) & 1u)) >> 16;
}
__device__ __forceinline__ float bfbits2f(u32 b) {
  return __uint_as_float(b << 16);
}
__device__ __forceinline__ float fmed3(float a, float b, float c) {
  return __builtin_amdgcn_fmed3f(a, b, c);
}

// ---- prep: swizzled hi/lo bf16 codebook + exact numpy-replica b2 ----
// off(g,p,f,r,e) = g*2048 + p*1024 + f*512 + r*32 + e   (u16 units)
//   g=row>>4, r=row&15, p=plane(0 hi,1 lo), f=k>>5, e=k&31.
// A wave's 16-row fragment load at fixed (p,f) is 1KB contiguous.
__global__ void vq_prep(const float* __restrict__ emb, u16* __restrict__ swz,
                        float* __restrict__ b2) {
#pragma clang fp contract(off)
  const int n = blockIdx.x * 256 + threadIdx.x;
  if (n >= NEMB) return;
  const float* e = emb + n * DIM;
  float rr[8];
#pragma unroll
  for (int j = 0; j < 8; ++j) {
    float acc = e[j] * e[j];
#pragma unroll
    for (int i = 8; i < DIM; i += 8) acc = acc + e[i + j] * e[i + j];
    rr[j] = acc;
  }
  b2[n] = ((rr[0] + rr[1]) + (rr[2] + rr[3])) + ((rr[4] + rr[5]) + (rr[6] + rr[7]));
  const int g = n >> 4, r = n & 15;
  u16* gb = swz + (g << 11) + (r << 5);
#pragma unroll
  for (int k = 0; k < DIM; ++k) {
    const u32 h = f2bfbits(e[k]);
    const float res = e[k] - bfbits2f(h);  // exact (Sterbenz)
    const int off = ((k >> 5) << 9) + (k & 31);
    gb[off] = (u16)h;                     // hi plane
    gb[1024 + off] = (u16)f2bfbits(res);  // lo plane
  }
}

// ---- main kernel: 64 rows/block.
// wave wv: row-half rh=wv&1 (tiles 2rh,2rh+1), col-half ch=wv>>1 (256 cols).
__global__ __launch_bounds__(256, 1) void vq_mfma(
    const float* __restrict__ in, const float* __restrict__ emb,
    const u16* __restrict__ swz, const float* __restrict__ b2g,
    float* __restrict__ out) {
#pragma clang fp contract(off)
  __shared__ float xs[ROWS][DIM + 2];
  __shared__ float a2s[ROWS];
  __shared__ float b2s[NEMB];
  __shared__ float wsv1[ROWS][2], wsv2[ROWS][2], wsv3[ROWS][2];
  __shared__ int win[ROWS];
  __shared__ int queue[ROWS];
  __shared__ int qcnt;

  const int tid = threadIdx.x;
  const int blk = blockIdx.x;
  const int b = blk >> 6;
  const int hw0 = (blk & 63) << 6;
  const float* xbase = in + ((size_t)b << 18) + hw0;

  for (int i = tid; i < NEMB; i += 256) b2s[i] = b2g[i];
  if (tid == 0) qcnt = 0;

  {  // stage x tile (64 consecutive floats per wave = coalesced)
    const int h = tid & 63, cg = tid >> 6;
#pragma unroll
    for (int i = 0; i < 16; ++i) {
      const int c = cg + (i << 2);
      xs[h][c] = xbase[((size_t)c << 12) + h];
    }
  }
  __syncthreads();

  if (tid < ROWS) {  // a2 numpy pairwise-8 replica (re-rank input)
    const float* x = xs[tid];
    float rr[8];
#pragma unroll
    for (int j = 0; j < 8; ++j) {
      float acc = x[j] * x[j];
#pragma unroll
      for (int i = 8; i < DIM; i += 8) acc = acc + x[i + j] * x[i + j];
      rr[j] = acc;
    }
    a2s[tid] = ((rr[0] + rr[1]) + (rr[2] + rr[3])) + ((rr[4] + rr[5]) + (rr[6] + rr[7]));
  }

  const int lane = tid & 63;
  const int wv = tid >> 6;
  const int rh = wv & 1;   // row-half
  const int ch = wv >> 1;  // col-half
  const int rowl = lane & 15;
  const int quad = lane >> 4;

  // A fragments for this wave's 2 row-tiles: A[m=lane&15][k=quad*8+j]
  bf16x8 ah[2][2], al[2][2];
#pragma unroll
  for (int ta = 0; ta < 2; ++ta) {
    const int a = (rh << 1) + ta;
    const float* xr = xs[(a << 4) + rowl];
#pragma unroll
    for (int f = 0; f < 2; ++f) {
      const int k0 = (f << 5) + (quad << 3);
      bf16x8 vh, vl;
#pragma unroll
      for (int j = 0; j < 8; ++j) {
        const float xv = xr[k0 + j];
        const u32 h = f2bfbits(xv);
        const float res = xv - bfbits2f(h);  // exact
        vh[j] = (short)h;
        vl[j] = (short)f2bfbits(res);
      }
      ah[ta][f] = vh;
      al[ta][f] = vl;
    }
  }

  // ---- single pass over 256 cols: streaming top-3 MAXIMA of
  // acc' = dot - b2/2 (= -c2/2), index packed in low 9 mantissa bits ----
  float v1[8], v2[8], v3[8];
#pragma unroll
  for (int i = 0; i < 8; ++i) { v1[i] = -3.0e38f; v2[i] = -3.0e38f; v3[i] = -3.0e38f; }

  const u16* cbase = swz + ((size_t)(ch << 4) << 11);
  const int off = (rowl << 5) + (quad << 3);

  // 2-deep prefetch: two register sets, manual 2-phase rolled loop
  bf16x8 Ah0 = *(const bf16x8*)(cbase + off);
  bf16x8 Ah1 = *(const bf16x8*)(cbase + 512 + off);
  bf16x8 Al0 = *(const bf16x8*)(cbase + 1024 + off);
  bf16x8 Al1 = *(const bf16x8*)(cbase + 1536 + off);
  bf16x8 Bh0 = *(const bf16x8*)(cbase + 2048 + off);
  bf16x8 Bh1 = *(const bf16x8*)(cbase + 2048 + 512 + off);
  bf16x8 Bl0 = *(const bf16x8*)(cbase + 2048 + 1024 + off);
  bf16x8 Bl1 = *(const bf16x8*)(cbase + 2048 + 1536 + off);

#define VQ_PHASE(TT, PH0, PH1, PL0, PL1)                                      \
  {                                                                           \
    const bf16x8 bh0 = PH0, bh1 = PH1, bl0 = PL0, bl1 = PL1;                  \
    const int tn = (TT) + 2 < 16 ? (TT) + 2 : (TT); /* clamped reload */      \
    const u16* gb = cbase + (tn << 11);                                       \
    PH0 = *(const bf16x8*)(gb + off);                                         \
    PH1 = *(const bf16x8*)(gb + 512 + off);                                   \
    PL0 = *(const bf16x8*)(gb + 1024 + off);                                  \
    PL1 = *(const bf16x8*)(gb + 1536 + off);                                  \
    const int n = (ch << 8) + ((TT) << 4) + rowl;                             \
    const float nb2 = b2s[n] * -0.5f;                                         \
    const u32 nbits = (u32)n;                                                 \
    _Pragma("unroll") for (int ta = 0; ta < 2; ++ta) {                        \
      f32x4 acc = {nb2, nb2, nb2, nb2};                                       \
      acc = __builtin_amdgcn_mfma_f32_16x16x32_bf16(ah[ta][0], bh0, acc, 0, 0, 0); \
      acc = __builtin_amdgcn_mfma_f32_16x16x32_bf16(ah[ta][1], bh1, acc, 0, 0, 0); \
      acc = __builtin_amdgcn_mfma_f32_16x16x32_bf16(ah[ta][0], bl0, acc, 0, 0, 0); \
      acc = __builtin_amdgcn_mfma_f32_16x16x32_bf16(ah[ta][1], bl1, acc, 0, 0, 0); \
      acc = __builtin_amdgcn_mfma_f32_16x16x32_bf16(al[ta][0], bh0, acc, 0, 0, 0); \
      acc = __builtin_amdgcn_mfma_f32_16x16x32_bf16(al[ta][1], bh1, acc, 0, 0, 0); \
      _Pragma("unroll") for (int r = 0; r < 4; ++r) {                         \
        const int i = (ta << 2) + r;                                          \
        const float cp =                                                      \
            __uint_as_float((__float_as_uint(acc[r]) & 0xFFFFFE00u) | nbits); \
        v3[i] = fmed3(v2[i], cp, v3[i]);                                      \
        v2[i] = fmed3(v1[i], cp, v2[i]);                                      \
        v1[i] = fmaxf(v1[i], cp);                                             \
      }                                                                       \
    }                                                                         \
  }

#pragma unroll 1
  for (int t = 0; t < 16; t += 2) {
    VQ_PHASE(t, Ah0, Ah1, Al0, Al1);
    VQ_PHASE(t + 1, Bh0, Bh1, Bl0, Bl1);
  }
#undef VQ_PHASE

  // butterfly top-3 merge across the 16 column lanes (max domain); packed
  // values carry their indices, so the merge is pure med3/max
#pragma unroll
  for (int m = 1; m < 16; m <<= 1) {
#pragma unroll
    for (int i = 0; i < 8; ++i) {
      const float o1 = __shfl_xor(v1[i], m);
      const float o2 = __shfl_xor(v2[i], m);
      const float o3 = __shfl_xor(v3[i], m);
      // insert o1 (full), o2 (can't become v1), o3 (can only touch v3)
      v3[i] = fmed3(v2[i], o1, v3[i]);
      v2[i] = fmed3(v1[i], o1, v2[i]);
      v1[i] = fmaxf(v1[i], o1);
      v3[i] = fmed3(v2[i], o2, v3[i]);
      v2[i] = fmed3(v1[i], o2, v2[i]);
      v3[i] = fmaxf(v3[i], o3);
    }
  }
  if (rowl == 0) {  // publish per col-half slot
#pragma unroll
    for (int ta = 0; ta < 2; ++ta)
#pragma unroll
      for (int r = 0; r < 4; ++r) {
        const int row = (((rh << 1) + ta) << 4) + (quad << 2) + r;
        const int i = (ta << 2) + r;
        wsv1[row][ch] = v1[i]; wsv2[row][ch] = v2[i]; wsv3[row][ch] = v3[i];
      }
  }
  __syncthreads();

  // ---- cross-half merge + decision (max domain) ----
  if (tid < ROWS) {
    float m1 = wsv1[tid][0], m2v = wsv2[tid][0], m3 = wsv3[tid][0];
    const float u1 = wsv1[tid][1], u2 = wsv2[tid][1], u3 = wsv3[tid][1];
    m3 = fmed3(m2v, u1, m3);
    m2v = fmed3(m1, u1, m2v);
    m1 = fmaxf(m1, u1);
    m3 = fmed3(m2v, u2, m3);
    m2v = fmed3(m1, u2, m2v);
    m3 = fmaxf(m3, u3);
    const int j1 = (int)(__float_as_uint(m1) & 0x1FFu);
    const int j2 = (int)(__float_as_uint(m2v) & 0x1FFu);

    if (m2v < m1 - HMARGIN) {
      win[tid] = j1;  // unambiguous
    } else if (m3 < m1 - HMARGIN) {
      // true argmin in {j1,j2}: exact numpy fp32 re-rank, first-min tie rule
      const float a2 = a2s[tid];
      const float* x = xs[tid];
      const float* e1p = emb + (j1 << 6);
      const float* e2p = emb + (j2 << 6);
      float acc1 = 0.f, acc2 = 0.f;
#pragma unroll
      for (int j = 0; j < DIM; ++j) {
        acc1 = fmaf(x[j], e1p[j], acc1);
        acc2 = fmaf(x[j], e2p[j], acc2);
      }
      const float t1 = a2 + b2g[j1];
      const float t2 = a2 + b2g[j2];
      const float d1 = t1 - 2.0f * acc1;
      const float d2 = t2 - 2.0f * acc2;
      win[tid] = (d2 < d1 || (d2 == d1 && j2 < j1)) ? j2 : j1;
    } else {  // >=3 within margin: full exact rescan (rare)
      const int p = atomicAdd(&qcnt, 1);
      queue[p] = tid;
    }
  }
  __syncthreads();

  // ---- rare fallback: wave-cooperative bit-exact numpy fp32 rescan ----
  const int nq = qcnt;
  for (int qi = wv; qi < nq; qi += 4) {
    const int row = queue[qi];
    const float a2 = a2s[row];
    const float* x = xs[row];  // broadcast LDS reads
    float bd = 3.0e38f;
    int bi = 1 << 30;
#pragma unroll 1
    for (int c = 0; c < 8; ++c) {
      const int k = (c << 6) + lane;
      const float* e = emb + (k << 6);
      float acc = 0.f;
#pragma unroll
      for (int j = 0; j < DIM; ++j) acc = fmaf(x[j], e[j], acc);
      const float tt = a2 + b2g[k];  // fl(a2+b2)
      const float u = 2.0f * acc;    // fl(2ab)
      const float d = tt - u;        // fl(t-u)
      if (d < bd || (d == bd && k < bi)) { bd = d; bi = k; }
    }
#pragma unroll
    for (int m = 1; m < 64; m <<= 1) {  // numpy first-min tie rule
      const float od = __shfl_xor(bd, m);
      const int oi = __shfl_xor(bi, m);
      if (od < bd || (od == bd && oi < bi)) { bd = od; bi = oi; }
    }
    if (lane == 0) win[row] = bi;
  }
  __syncthreads();

  {  // fold q into xs in place: BATCHED (16 concurrent emb-row loads, one
     // drain) instead of the old serial win->load->write chain
    const int r0 = wv << 4;
    int wn[16];
#pragma unroll
    for (int r = 0; r < 16; ++r) wn[r] = win[r0 + r];
    float qv[16];
#pragma unroll
    for (int r = 0; r < 16; ++r) qv[r] = emb[(wn[r] << 6) + lane];
#pragma unroll
    for (int r = 0; r < 16; ++r) {
      const float xv = xs[r0 + r][lane];
      xs[r0 + r][lane] = xv + (qv[r] - xv);  // fl(x + fl(q-x))
    }
  }
  __syncthreads();

  {  // store: coalesced (lane = h)
    const int h = tid & 63, cg = tid >> 6;
    float* obase = out + ((size_t)b << 18) + hw0;
#pragma unroll
    for (int i = 0; i < 16; ++i) {
      const int c = cg + (i << 2);
      obase[((size_t)c << 12) + h] = xs[h][c];
    }
  }
}

// ---- fallback (R3, passed absmax 0.0): used only if ws too small ----
__global__ __launch_bounds__(256, 2) void vq_exact(
    const float* __restrict__ in, const float* __restrict__ emb,
    float* __restrict__ out, int nvec) {
#pragma clang fp contract(off)
  __shared__ float b2s[NEMB];
  for (int r = threadIdx.x; r < NEMB; r += 256) {
    const float* e = emb + r * DIM;
    float rr[8];
#pragma unroll
    for (int j = 0; j < 8; ++j) {
      float acc = e[j] * e[j];
#pragma unroll
      for (int i = 8; i < DIM; i += 8) acc = acc + e[i + j] * e[i + j];
      rr[j] = acc;
    }
    b2s[r] = ((rr[0] + rr[1]) + (rr[2] + rr[3])) + ((rr[4] + rr[5]) + (rr[6] + rr[7]));
  }
  __syncthreads();
  const int vec = blockIdx.x * 256 + threadIdx.x;
  if (vec >= nvec) return;
  const int b = vec >> 12, hw = vec & 4095;
  const float* xp = in + ((size_t)b << 18) + hw;
  float x[DIM];
#pragma unroll
  for (int j = 0; j < DIM; ++j) x[j] = xp[(size_t)j << 12];
  float a2;
  {
    float rr[8];
#pragma unroll
    for (int j = 0; j < 8; ++j) {
      float acc = x[j] * x[j];
#pragma unroll
      for (int i = 8; i < DIM; i += 8) acc = acc + x[i + j] * x[i + j];
      rr[j] = acc;
    }
    a2 = ((rr[0] + rr[1]) + (rr[2] + rr[3])) + ((rr[4] + rr[5]) + (rr[6] + rr[7]));
  }
  float best = 3.0e38f;
  int bi = 0;
  for (int k0 = 0; k0 < NEMB; k0 += 4) {
    const float *e0 = emb + ((k0 + 0) << 6), *e1 = emb + ((k0 + 1) << 6);
    const float *e2 = emb + ((k0 + 2) << 6), *e3 = emb + ((k0 + 3) << 6);
    float c0 = 0.f, c1 = 0.f, c2 = 0.f, c3 = 0.f;
#pragma unroll
    for (int j = 0; j < DIM; ++j) {
      const float xj = x[j];
      c0 = fmaf(xj, e0[j], c0); c1 = fmaf(xj, e1[j], c1);
      c2 = fmaf(xj, e2[j], c2); c3 = fmaf(xj, e3[j], c3);
    }
    float cc[4] = {c0, c1, c2, c3};
#pragma unroll
    for (int q = 0; q < 4; ++q) {
      const float t = a2 + b2s[k0 + q];
      const float u = 2.0f * cc[q];
      const float d = t - u;
      if (d < best) { best = d; bi = k0 + q; }
    }
  }
  const float* ew = emb + (bi << 6);
  float* op = out + ((size_t)b << 18) + hw;
#pragma unroll
  for (int c = 0; c < DIM; ++c) {
    const float xv = x[c];
    op[(size_t)c << 12] = xv + (ew[c] - xv);
  }
}

extern "C" void kernel_launch(void* const* d_in, const int* in_sizes, int n_in,
                              void* d_out, int out_size, void* d_ws, size_t ws_size,
                              hipStream_t stream) {
  const float* in;
  const float* emb;
  int in_elems;
  if (n_in >= 2 && in_sizes[0] == NEMB * DIM && in_sizes[1] != NEMB * DIM) {
    emb = (const float*)d_in[0]; in = (const float*)d_in[1]; in_elems = in_sizes[1];
  } else {
    in = (const float*)d_in[0]; emb = (const float*)d_in[1]; in_elems = in_sizes[0];
  }
  float* out = (float*)d_out;
  const int nvec = in_elems / DIM;
  const size_t swzB = (size_t)NEMB * DIM * 2 * sizeof(u16);  // hi+lo swizzled
  const size_t need = swzB + NEMB * sizeof(float);

  if (ws_size >= need && d_ws != nullptr && (nvec % ROWS) == 0 &&
      (in_elems % (DIM * 4096)) == 0) {
    u16* swz = (u16*)d_ws;
    float* b2 = (float*)((char*)d_ws + swzB);
    vq_prep<<<dim3(2), dim3(256), 0, stream>>>(emb, swz, b2);
    vq_mfma<<<dim3(nvec / ROWS), dim3(256), 0, stream>>>(in, emb, swz, b2, out);
  } else {
    vq_exact<<<dim3((nvec + 255) / 256), dim3(256), 0, stream>>>(in, emb, out, nvec);
  }
}